// Round 2
// baseline (244.500 us; speedup 1.0000x reference)
//
#include <hip/hip_runtime.h>
#include <hip/hip_bf16.h>
#include <math.h>

#define L_TAU_C 0.8f

typedef __attribute__((ext_vector_type(8))) _Float16 half8_t;

__device__ __forceinline__ float sigmoidf_(float x) {
    return 1.0f / (1.0f + __expf(-x));
}

// ---------------------------------------------------------------------------
// Kernel 1: transpose x [128][4096][20] f32 -> xT [128][20][4096] f16.
// Thread = one pixel: 5 coalesced float4 reads; 20 ushort stores, each wave
// writing 128 contiguous bytes per t. ~63 MB total traffic.
// ---------------------------------------------------------------------------
__global__ __launch_bounds__(256) void k_transpose16(const float* __restrict__ x,
                                                     _Float16* __restrict__ xT) {
    int gp = blockIdx.x * 256 + threadIdx.x;      // 0..524287
    int b = gp >> 12, p = gp & 4095;
    const float4* src = reinterpret_cast<const float4*>(x + (size_t)gp * 20);
    float v[20];
#pragma unroll
    for (int k = 0; k < 5; ++k) {
        float4 q = src[k];
        v[4 * k + 0] = q.x; v[4 * k + 1] = q.y; v[4 * k + 2] = q.z; v[4 * k + 3] = q.w;
    }
    _Float16* dst = xT + (size_t)b * 20 * 4096 + p;
#pragma unroll
    for (int t = 0; t < 20; ++t) dst[(size_t)t * 4096] = (_Float16)v[t];
}

// ---------------------------------------------------------------------------
// Kernel 2: fused conv + SNU(s1,y1) + maxpool + partial FC dot.
// Grid = 768 (b,ch) blocks (3/CU), block = 192 threads (3 waves), 189 active:
// thread = (pool row r 0..26, col group cg 0..6) -> 2 conv rows x 8 conv cols.
// xs LDS tile [64 rows][64 floats], XOR-swizzled in 16B units with
// u' = u ^ ((R>>1)&15)  (R>>1: output rows step by 2 -> R-parity is uniform
// across the wave; R-based XOR would leave half the banks idle).
// Conv weights are read via block-uniform global loads -> SGPRs (no LDS).
// s1/y1 live in registers across t. Writes part[t][b][ch][2].
// ---------------------------------------------------------------------------
template<int XMODE>   // 1 = f16 transposed input, 0 = strided fallback
__global__ __launch_bounds__(192) void k_conv_snu(
    const float* __restrict__ x,      // [128][4096][20]
    const _Float16* __restrict__ xT,  // [128][20][4096]
    const float* __restrict__ Wc,     // [6][1][10][10]
    const float* __restrict__ bc,     // [6]
    const float* __restrict__ W2,     // [4374][2]
    float* __restrict__ part)         // [20][128][6][2]
{
    __shared__ float xs[64 * 64];     // 16 KB, swizzled
    __shared__ float red[6];
    float4* xs4 = reinterpret_cast<float4*>(xs);

    const int tid = threadIdx.x;
    const int bi = blockIdx.x;
    const int xcd = bi & 7, slot = bi >> 3;
    const int b = (slot / 6) * 8 + xcd;   // all 6 ch of b on same XCD
    const int ch = slot % 6;

    const bool active = tid < 189;
    const int r = tid / 7;            // pool row 0..26
    const int cg = tid % 7;           // col group 0..6 (8 conv cols each)
    const int row0 = 2 * r;

    float s1[2][8], y1[2][8];
#pragma unroll
    for (int i = 0; i < 2; ++i)
#pragma unroll
        for (int j = 0; j < 8; ++j) { s1[i][j] = 0.f; y1[i][j] = 0.f; }

    const float bch = bc[ch];

    // FC weights for this thread's 4 pool cols (pc = cg*4+pj); pc>=27 masked 0.
    float w2r[4][2];
#pragma unroll
    for (int pj = 0; pj < 4; ++pj) { w2r[pj][0] = 0.f; w2r[pj][1] = 0.f; }
    if (active) {
#pragma unroll
        for (int pj = 0; pj < 4; ++pj) {
            int pc = cg * 4 + pj;
            if (pc < 27) {
                int f0 = ch * 729 + r * 27 + pc;
                w2r[pj][0] = W2[(size_t)f0 * 2 + 0];
                w2r[pj][1] = W2[(size_t)f0 * 2 + 1];
            }
        }
    }

    const int wave = tid >> 6, lane = tid & 63;
    const float* wb = Wc + ch * 100;   // block-uniform -> SGPR loads

    for (int t = 0; t < 20; ++t) {
        __syncthreads();   // xs + red of t-1 fully consumed
        // ---- stage x_t into swizzled xs ----
        if (XMODE == 1) {
            const _Float16* src = xT + ((size_t)b * 20 + t) * 4096;
#pragma unroll
            for (int k = 0; k < 3; ++k) {
                int e = tid + k * 192;          // 512 x half8 units
                if (e < 512) {
                    half8_t hv = *reinterpret_cast<const half8_t*>(src + e * 8);
                    int R = e >> 3, h = e & 7;
                    int sw = (R >> 1) & 15;
                    float4 fa, fb;
                    fa.x = (float)hv[0]; fa.y = (float)hv[1];
                    fa.z = (float)hv[2]; fa.w = (float)hv[3];
                    fb.x = (float)hv[4]; fb.y = (float)hv[5];
                    fb.z = (float)hv[6]; fb.w = (float)hv[7];
                    xs4[(R << 4) + ((2 * h) ^ sw)] = fa;
                    xs4[(R << 4) + ((2 * h + 1) ^ sw)] = fb;
                }
            }
        } else {
            for (int k = 0; k < 22; ++k) {
                int p = tid + k * 192;
                if (p < 4096) {
                    int R = p >> 6, c = p & 63;
                    int sw = (R >> 1) & 15;
                    float vv = x[((size_t)b * 4096 + p) * 20 + t];
                    xs[(R << 6) + ((((c >> 2) ^ sw) & 15) << 2) + (c & 3)] = vv;
                }
            }
        }
        __syncthreads();

        float p0 = 0.f, p1 = 0.f;
        if (active) {
            float c0[8], c1[8];
#pragma unroll
            for (int j = 0; j < 8; ++j) { c0[j] = 0.f; c1[j] = 0.f; }

#pragma unroll
            for (int xr = 0; xr < 11; ++xr) {
                const int R = row0 + xr;
                const int sw = (R >> 1) & 15;
                float4 sg[5];
#pragma unroll
                for (int q = 0; q < 5; ++q)
                    sg[q] = xs4[(R << 4) + (((2 * cg + q) ^ sw) & 15)];
                const float* seg = reinterpret_cast<const float*>(sg);
                if (xr <= 9) {
#pragma unroll
                    for (int kc = 0; kc < 10; ++kc) {
                        float w = wb[xr * 10 + kc];
#pragma unroll
                        for (int j = 0; j < 8; ++j) c0[j] += seg[j + kc] * w;
                    }
                }
                if (xr >= 1) {
#pragma unroll
                    for (int kc = 0; kc < 10; ++kc) {
                        float w = wb[(xr - 1) * 10 + kc];
#pragma unroll
                        for (int j = 0; j < 8; ++j) c1[j] += seg[j + kc] * w;
                    }
                }
            }
            // SNU: s = relu(c + 0.8*s*(1-y)); y = sigmoid(s + bc)
#pragma unroll
            for (int j = 0; j < 8; ++j) {
                float sa = fmaxf(c0[j] + L_TAU_C * s1[0][j] * (1.f - y1[0][j]), 0.f);
                float sb = fmaxf(c1[j] + L_TAU_C * s1[1][j] * (1.f - y1[1][j]), 0.f);
                s1[0][j] = sa; s1[1][j] = sb;
                y1[0][j] = sigmoidf_(sa + bch);
                y1[1][j] = sigmoidf_(sb + bch);
            }
            // maxpool 2x2 + partial FC dot (junk cols 54/55 land in pc=27 -> w2r=0)
#pragma unroll
            for (int pj = 0; pj < 4; ++pj) {
                float h = fmaxf(fmaxf(y1[0][2 * pj], y1[0][2 * pj + 1]),
                                fmaxf(y1[1][2 * pj], y1[1][2 * pj + 1]));
                p0 += h * w2r[pj][0];
                p1 += h * w2r[pj][1];
            }
        }
        // block reduce p0,p1 (inactive lanes contribute 0)
#pragma unroll
        for (int off = 32; off >= 1; off >>= 1) {
            p0 += __shfl_down(p0, off);
            p1 += __shfl_down(p1, off);
        }
        if (lane == 0) { red[wave * 2] = p0; red[wave * 2 + 1] = p1; }
        __syncthreads();
        if (tid == 0) {
            float q0 = red[0] + red[2] + red[4];
            float q1 = red[1] + red[3] + red[5];
            float* dst = part + ((size_t)t * 128 + b) * 12 + ch * 2;
            dst[0] = q0; dst[1] = q1;
        }
    }
}

// ---------------------------------------------------------------------------
// Kernel 3: s2/y2 recurrence, out_rec, m, loss, acc. One block, 128 threads.
// ---------------------------------------------------------------------------
__global__ __launch_bounds__(128) void k_final(const float* __restrict__ part,
                                               const void* __restrict__ yraw,
                                               const float* __restrict__ b2,
                                               float* __restrict__ out) {
    __shared__ float red[4];
    const int b = threadIdx.x;  // 0..127

    // labels may be int64 (reference) or int32: detect.
    const int* yi = (const int*)yraw;
    bool i64 = true;
    for (int k = 0; k < 64; ++k) {
        if (yi[2 * k + 1] != 0) { i64 = false; break; }
    }
    int lbl = i64 ? (int)((const long long*)yraw)[b] : yi[b];

    float b20 = b2[0], b21 = b2[1];
    float s20 = 0.f, s21 = 0.f, y20 = 0.f, y21 = 0.f, m0 = 0.f, m1 = 0.f;
    float* orec = out + 257 + b * 42;
    orec[0] = 0.f; orec[1] = 0.f;
    for (int t = 0; t < 20; ++t) {
        const float4* pp = reinterpret_cast<const float4*>(part + ((size_t)t * 128 + b) * 12);
        float4 a = pp[0], c = pp[1], d = pp[2];
        float sum0 = a.x + a.z + c.x + c.z + d.x + d.z;
        float sum1 = a.y + a.w + c.y + c.w + d.y + d.w;
        s20 = fmaxf(sum0 + L_TAU_C * s20 * (1.f - y20), 0.f);
        s21 = fmaxf(sum1 + L_TAU_C * s21 * (1.f - y21), 0.f);
        y20 = sigmoidf_(s20 + b20);
        y21 = sigmoidf_(s21 + b21);
        orec[(t + 1) * 2 + 0] = y20;
        orec[(t + 1) * 2 + 1] = y21;
        m0 += y20; m1 += y21;
    }
    m0 *= 0.05f; m1 *= 0.05f;
    out[1 + b * 2 + 0] = m0;
    out[1 + b * 2 + 1] = m1;

    float mx = fmaxf(m0, m1);
    float lse = mx + logf(expf(m0 - mx) + expf(m1 - mx));
    float lossc = -(((lbl != 0) ? m1 : m0) - lse);
    int pred = (m1 > m0) ? 1 : 0;
    float accc = (pred == lbl) ? 1.f : 0.f;
#pragma unroll
    for (int off = 32; off >= 1; off >>= 1) {
        lossc += __shfl_down(lossc, off);
        accc += __shfl_down(accc, off);
    }
    if ((b & 63) == 0) { red[(b >> 6) * 2] = lossc; red[(b >> 6) * 2 + 1] = accc; }
    __syncthreads();
    if (b == 0) {
        out[0] = (red[0] + red[2]) * (1.f / 128.f);
        out[5633] = (red[1] + red[3]) * (1.f / 128.f);
    }
}

extern "C" void kernel_launch(void* const* d_in, const int* in_sizes, int n_in,
                              void* d_out, int out_size, void* d_ws, size_t ws_size,
                              hipStream_t stream) {
    const float* x  = (const float*)d_in[0];
    const void*  y  = d_in[1];
    const float* Wc = (const float*)d_in[2];
    const float* bc = (const float*)d_in[3];
    const float* W2 = (const float*)d_in[4];
    const float* b2 = (const float*)d_in[5];
    float* out = (float*)d_out;

    const size_t xt_bytes = (size_t)128 * 20 * 4096 * 2;   // 20,971,520
    const size_t part_bytes = (size_t)20 * 128 * 6 * 2 * 4; // 245,760
    const int use16 = (ws_size >= xt_bytes + part_bytes) ? 1 : 0;

    _Float16* xT = (_Float16*)d_ws;
    float* part = use16 ? (float*)((char*)d_ws + xt_bytes) : (float*)d_ws;

    if (use16) {
        k_transpose16<<<2048, 256, 0, stream>>>(x, xT);
        k_conv_snu<1><<<768, 192, 0, stream>>>(x, xT, Wc, bc, W2, part);
    } else {
        k_conv_snu<0><<<768, 192, 0, stream>>>(x, (const _Float16*)d_ws, Wc, bc, W2, part);
    }
    k_final<<<1, 128, 0, stream>>>(part, y, b2, out);
}